// Round 19
// baseline (1673.632 us; speedup 1.0000x reference)
//
#include <hip/hip_runtime.h>

#define N_NODES 100000
#define N_EDGES 1600000
#define T_STEPS 6
#define FDIM    64
#define SEG     (T_STEPS * N_NODES)
#define C2      0.01f
#define PADF    68   // LDS row stride: 17 quads, 16B-aligned float4 rows
#define RFL __builtin_amdgcn_readfirstlane

// Build per-(t,dst)-segment linked lists over edges. One atomicExch per edge
// on the 2.4MB head array (L2-resident).
__global__ __launch_bounds__(256) void k_build(
    const int* __restrict__ dst, const int* __restrict__ tix,
    int* __restrict__ head, int* __restrict__ nxt)
{
  const int e = blockIdx.x * blockDim.x + threadIdx.x;
  if (e >= N_EDGES) return;
  const int key = tix[e] * N_NODES + dst[e];
  nxt[e] = atomicExch(&head[key], e);
}

// ===== VERBATIM r17 k_sum6 (scalarized chains, 131us -- measured best;
// r18's 12-chain variant regressed to 138us via RFL-VALU + occupancy). =====
__global__ __launch_bounds__(256) void k_sum6(
    const float* __restrict__ feat, const int* __restrict__ src,
    const int* __restrict__ head, const int* __restrict__ nxt,
    float* __restrict__ sums, float* __restrict__ cnt)
{
  const int lane = threadIdx.x & 63;
  const int n = blockIdx.x * (blockDim.x >> 6) + (threadIdx.x >> 6);
  if (n >= N_NODES) return;

  int e0 = RFL(head[(size_t)0 * N_NODES + n]);
  int e1 = RFL(head[(size_t)1 * N_NODES + n]);
  int e2 = RFL(head[(size_t)2 * N_NODES + n]);
  int e3 = RFL(head[(size_t)3 * N_NODES + n]);
  int e4 = RFL(head[(size_t)4 * N_NODES + n]);
  int e5 = RFL(head[(size_t)5 * N_NODES + n]);

  float v0 = 0.f, v1 = 0.f, v2 = 0.f, v3 = 0.f, v4 = 0.f, v5 = 0.f;
  int c0 = 0, c1 = 0, c2 = 0, c3 = 0, c4 = 0, c5 = 0;

  while ((e0 >= 0) | (e1 >= 0) | (e2 >= 0) | (e3 >= 0) | (e4 >= 0) | (e5 >= 0)) {
    const int a0 = e0 < 0 ? 0 : e0, a1 = e1 < 0 ? 0 : e1, a2 = e2 < 0 ? 0 : e2;
    const int a3 = e3 < 0 ? 0 : e3, a4 = e4 < 0 ? 0 : e4, a5 = e5 < 0 ? 0 : e5;

    const int s0 = RFL(src[a0]);
    const int s1 = RFL(src[a1]);
    const int s2 = RFL(src[a2]);
    const int s3 = RFL(src[a3]);
    const int s4 = RFL(src[a4]);
    const int s5 = RFL(src[a5]);
    const int x0 = RFL(nxt[a0]);
    const int x1 = RFL(nxt[a1]);
    const int x2 = RFL(nxt[a2]);
    const int x3 = RFL(nxt[a3]);
    const int x4 = RFL(nxt[a4]);
    const int x5 = RFL(nxt[a5]);

    const float f0 = feat[(size_t)s0 * FDIM + lane];
    const float f1 = feat[(size_t)s1 * FDIM + lane];
    const float f2 = feat[(size_t)s2 * FDIM + lane];
    const float f3 = feat[(size_t)s3 * FDIM + lane];
    const float f4 = feat[(size_t)s4 * FDIM + lane];
    const float f5 = feat[(size_t)s5 * FDIM + lane];

    v0 += (e0 >= 0) ? f0 : 0.0f;  c0 += (e0 >= 0);  e0 = (e0 >= 0) ? x0 : -1;
    v1 += (e1 >= 0) ? f1 : 0.0f;  c1 += (e1 >= 0);  e1 = (e1 >= 0) ? x1 : -1;
    v2 += (e2 >= 0) ? f2 : 0.0f;  c2 += (e2 >= 0);  e2 = (e2 >= 0) ? x2 : -1;
    v3 += (e3 >= 0) ? f3 : 0.0f;  c3 += (e3 >= 0);  e3 = (e3 >= 0) ? x3 : -1;
    v4 += (e4 >= 0) ? f4 : 0.0f;  c4 += (e4 >= 0);  e4 = (e4 >= 0) ? x4 : -1;
    v5 += (e5 >= 0) ? f5 : 0.0f;  c5 += (e5 >= 0);  e5 = (e5 >= 0) ? x5 : -1;
  }

  sums[((size_t)0 * N_NODES + n) * FDIM + lane] = v0;
  sums[((size_t)1 * N_NODES + n) * FDIM + lane] = v1;
  sums[((size_t)2 * N_NODES + n) * FDIM + lane] = v2;
  sums[((size_t)3 * N_NODES + n) * FDIM + lane] = v3;
  sums[((size_t)4 * N_NODES + n) * FDIM + lane] = v4;
  sums[((size_t)5 * N_NODES + n) * FDIM + lane] = v5;
  if (lane == 0) {
    cnt[(size_t)0 * N_NODES + n] = (float)c0;
    cnt[(size_t)1 * N_NODES + n] = (float)c1;
    cnt[(size_t)2 * N_NODES + n] = (float)c2;
    cnt[(size_t)3 * N_NODES + n] = (float)c3;
    cnt[(size_t)4 * N_NODES + n] = (float)c4;
    cnt[(size_t)5 * N_NODES + n] = (float)c5;
  }
}

// Software-pipelined gemm: two STATIC plane buffers (A/B), fully unrolled
// 6-round schedule with compile-time buffer names (r14's failure was
// runtime-indexed LDS + guarded prefetch; r16's remaining stall was the
// fully-exposed stage between barrier and compute). Per round: issue plane
// t+1's 4 float4 loads -> compute plane t from the other buffer (~2200cy of
// fma hides the L3 latency) -> write regs -> ONE barrier. Same LDS (34.8KB,
// 4 blocks/CU), same loads, same t-ascending order; pass A/B expression
// trees verbatim r1/r16 -> bit-identical output.
#define STAGE_LOAD(R, T)                                                     \
  _Pragma("unroll") for (int it = 0; it < 4; ++it) {                         \
    const int item = tid + it * 256;                                         \
    const int q = item & 15, u = item >> 4;                                  \
    const int nn = n0 + u;                                                   \
    R[it] = make_float4(0.f, 0.f, 0.f, 0.f);                                 \
    if (nn < N_NODES)                                                        \
      R[it] = *(const float4*)(sums + ((size_t)(T) * N_NODES + nn) * FDIM + q * 4); \
  }

#define STAGE_WRITE(BUF, R)                                                  \
  _Pragma("unroll") for (int it = 0; it < 4; ++it) {                         \
    const int item = tid + it * 256;                                         \
    const int q = item & 15, u = item >> 4;                                  \
    *(float4*)(&BUF[u * PADF + q * 4]) = R[it];                              \
  }

#define COMPUTE(BUF, T) {                                                    \
  const float c  = cnt[(size_t)(T) * N_NODES + n];                           \
  const float rc = 1.0f / fmaxf(c, 1.0f);                                    \
  const float4* row = (const float4*)(&BUF[lane * PADF]);                    \
  float ss = 0.0f;                                                           \
  _Pragma("unroll") for (int q = 0; q < FDIM / 4; ++q) {                     \
    float4 v = row[q];                                                       \
    float m0 = v.x * rc, m1 = v.y * rc, m2 = v.z * rc, m3 = v.w * rc;        \
    ss += m0 * m0 + m1 * m1 + m2 * m2 + m3 * m3;                             \
  }                                                                          \
  const float norm = 1.0f - C2 * ss;                                         \
  const float s = rc / norm;                                                 \
  _Pragma("unroll") for (int q8 = 0; q8 < FDIM / 8; ++q8) {                  \
    const float4 a = row[q8 * 2 + 0];                                        \
    const float4 b4 = row[q8 * 2 + 1];                                       \
    const float hv[8] = {a.x, a.y, a.z, a.w, b4.x, b4.y, b4.z, b4.w};        \
    const float* wr = W + ((size_t)(T) * FDIM + q8 * 8) * OUTF + jb;         \
    _Pragma("unroll") for (int i = 0; i < 8; ++i) {                          \
      const float hs = hv[i] * s;                                            \
      _Pragma("unroll") for (int j = 0; j < JBLK; ++j)                       \
        acc[j] = fmaf(hs, wr[i * OUTF + j], acc[j]);                         \
    }                                                                        \
  }                                                                          \
}

template <int OUTF, int JBLK>
__global__ __launch_bounds__(256) void k_gemm_pipe(
    const float* __restrict__ sums, const float* __restrict__ cnt,
    const float* __restrict__ W, const float* __restrict__ bias,
    float* __restrict__ out)
{
  __shared__ float ldsA[64 * PADF];   // 17408 B
  __shared__ float ldsB[64 * PADF];   // 17408 B
  const int tid = threadIdx.x;
  const int lane = tid & 63;
  const int n0 = blockIdx.x * 64;
  const int jb = RFL(tid >> 6) * JBLK;

  int n = n0 + lane;
  const bool valid = (n < N_NODES);
  if (!valid) n = N_NODES - 1;

  float acc[JBLK];
  #pragma unroll
  for (int j = 0; j < JBLK; ++j) acc[j] = bias[jb + j];

  float4 ra[4], rb[4];

  STAGE_LOAD(ra, 0); STAGE_WRITE(ldsA, ra); __syncthreads();
  STAGE_LOAD(rb, 1); COMPUTE(ldsA, 0); STAGE_WRITE(ldsB, rb); __syncthreads();
  STAGE_LOAD(ra, 2); COMPUTE(ldsB, 1); STAGE_WRITE(ldsA, ra); __syncthreads();
  STAGE_LOAD(rb, 3); COMPUTE(ldsA, 2); STAGE_WRITE(ldsB, rb); __syncthreads();
  STAGE_LOAD(ra, 4); COMPUTE(ldsB, 3); STAGE_WRITE(ldsA, ra); __syncthreads();
  STAGE_LOAD(rb, 5); COMPUTE(ldsA, 4); STAGE_WRITE(ldsB, rb); __syncthreads();
  COMPUTE(ldsB, 5);

  if (valid) {
    float* o = out + (size_t)n * OUTF + jb;
    #pragma unroll
    for (int j = 0; j < JBLK; ++j) o[j] = fmaxf(acc[j], 0.0f);
  }
}

extern "C" void kernel_launch(void* const* d_in, const int* in_sizes, int n_in,
                              void* d_out, int out_size, void* d_ws, size_t ws_size,
                              hipStream_t stream) {
  const float* x  = (const float*)d_in[0];
  const int*  ei  = (const int*)d_in[1];
  const int*  tix = (const int*)d_in[2];
  const float* W1 = (const float*)d_in[3];
  const float* b1 = (const float*)d_in[4];
  const float* W2 = (const float*)d_in[5];
  const float* b2 = (const float*)d_in[6];

  const int* src = ei;
  const int* dst = ei + N_EDGES;

  // Workspace: head[SEG] | nxt[NE] | sums[SEG*64] | cnt[SEG] | h1[NN*64]
  int*   head = (int*)d_ws;
  int*   nxt  = head + SEG;
  float* sums = (float*)(nxt + N_EDGES);
  float* cnt  = sums + (size_t)SEG * FDIM;
  float* h1   = cnt + SEG;

  const int sum_grid = (N_NODES + 3) / 4;        // k_sum6: 4 waves/block
  const int ngrp     = (N_NODES + 63) / 64;      // 1563 64-node groups

  hipMemsetAsync(head, 0xFF, (size_t)SEG * sizeof(int), stream);
  k_build<<<(N_EDGES + 255) / 256, 256, 0, stream>>>(dst, tix, head, nxt);

  // Layer 1
  k_sum6<<<sum_grid, 256, 0, stream>>>(x, src, head, nxt, sums, cnt);
  k_gemm_pipe<64, 16><<<ngrp, 256, 0, stream>>>(sums, cnt, W1, b1, h1);

  // Layer 2 (same edge lists; cnt identical but rewritten -- harmless)
  k_sum6<<<sum_grid, 256, 0, stream>>>(h1, src, head, nxt, sums, cnt);
  k_gemm_pipe<16, 4><<<ngrp, 256, 0, stream>>>(sums, cnt, W2, b2, (float*)d_out);
}

// Round 20
// 460.234 us; speedup vs baseline: 3.6365x; 3.6365x over previous
//
#include <hip/hip_runtime.h>

#define N_NODES 100000
#define N_PAD   100032   // 1563 * 64 -- padded node count for guard-free staging
#define N_EDGES 1600000
#define T_STEPS 6
#define FDIM    64
#define SEG     (T_STEPS * N_NODES)
#define C2      0.01f
#define PADF    68   // LDS row stride: 17 quads, 16B-aligned float4 rows
#define RFL __builtin_amdgcn_readfirstlane

// Build per-(t,dst)-segment linked lists over edges. One atomicExch per edge
// on the 2.4MB head array (L2-resident).
__global__ __launch_bounds__(256) void k_build(
    const int* __restrict__ dst, const int* __restrict__ tix,
    int* __restrict__ head, int* __restrict__ nxt)
{
  const int e = blockIdx.x * blockDim.x + threadIdx.x;
  if (e >= N_EDGES) return;
  const int key = tix[e] * N_NODES + dst[e];
  nxt[e] = atomicExch(&head[key], e);
}

// ===== VERBATIM r17 k_sum6 (scalarized chains, 131us -- measured best).
// r18 (12 chains): 138us, RFL-VALU + occupancy loss. r11 (24): 332us. =====
// NOTE: sums rows are written at stride N_PAD so gemm staging is guard-free.
__global__ __launch_bounds__(256) void k_sum6(
    const float* __restrict__ feat, const int* __restrict__ src,
    const int* __restrict__ head, const int* __restrict__ nxt,
    float* __restrict__ sums, float* __restrict__ cnt)
{
  const int lane = threadIdx.x & 63;
  const int n = blockIdx.x * (blockDim.x >> 6) + (threadIdx.x >> 6);
  if (n >= N_NODES) return;

  int e0 = RFL(head[(size_t)0 * N_NODES + n]);
  int e1 = RFL(head[(size_t)1 * N_NODES + n]);
  int e2 = RFL(head[(size_t)2 * N_NODES + n]);
  int e3 = RFL(head[(size_t)3 * N_NODES + n]);
  int e4 = RFL(head[(size_t)4 * N_NODES + n]);
  int e5 = RFL(head[(size_t)5 * N_NODES + n]);

  float v0 = 0.f, v1 = 0.f, v2 = 0.f, v3 = 0.f, v4 = 0.f, v5 = 0.f;
  int c0 = 0, c1 = 0, c2 = 0, c3 = 0, c4 = 0, c5 = 0;

  while ((e0 >= 0) | (e1 >= 0) | (e2 >= 0) | (e3 >= 0) | (e4 >= 0) | (e5 >= 0)) {
    const int a0 = e0 < 0 ? 0 : e0, a1 = e1 < 0 ? 0 : e1, a2 = e2 < 0 ? 0 : e2;
    const int a3 = e3 < 0 ? 0 : e3, a4 = e4 < 0 ? 0 : e4, a5 = e5 < 0 ? 0 : e5;

    const int s0 = RFL(src[a0]);
    const int s1 = RFL(src[a1]);
    const int s2 = RFL(src[a2]);
    const int s3 = RFL(src[a3]);
    const int s4 = RFL(src[a4]);
    const int s5 = RFL(src[a5]);
    const int x0 = RFL(nxt[a0]);
    const int x1 = RFL(nxt[a1]);
    const int x2 = RFL(nxt[a2]);
    const int x3 = RFL(nxt[a3]);
    const int x4 = RFL(nxt[a4]);
    const int x5 = RFL(nxt[a5]);

    const float f0 = feat[(size_t)s0 * FDIM + lane];
    const float f1 = feat[(size_t)s1 * FDIM + lane];
    const float f2 = feat[(size_t)s2 * FDIM + lane];
    const float f3 = feat[(size_t)s3 * FDIM + lane];
    const float f4 = feat[(size_t)s4 * FDIM + lane];
    const float f5 = feat[(size_t)s5 * FDIM + lane];

    v0 += (e0 >= 0) ? f0 : 0.0f;  c0 += (e0 >= 0);  e0 = (e0 >= 0) ? x0 : -1;
    v1 += (e1 >= 0) ? f1 : 0.0f;  c1 += (e1 >= 0);  e1 = (e1 >= 0) ? x1 : -1;
    v2 += (e2 >= 0) ? f2 : 0.0f;  c2 += (e2 >= 0);  e2 = (e2 >= 0) ? x2 : -1;
    v3 += (e3 >= 0) ? f3 : 0.0f;  c3 += (e3 >= 0);  e3 = (e3 >= 0) ? x3 : -1;
    v4 += (e4 >= 0) ? f4 : 0.0f;  c4 += (e4 >= 0);  e4 = (e4 >= 0) ? x4 : -1;
    v5 += (e5 >= 0) ? f5 : 0.0f;  c5 += (e5 >= 0);  e5 = (e5 >= 0) ? x5 : -1;
  }

  sums[((size_t)0 * N_PAD + n) * FDIM + lane] = v0;
  sums[((size_t)1 * N_PAD + n) * FDIM + lane] = v1;
  sums[((size_t)2 * N_PAD + n) * FDIM + lane] = v2;
  sums[((size_t)3 * N_PAD + n) * FDIM + lane] = v3;
  sums[((size_t)4 * N_PAD + n) * FDIM + lane] = v4;
  sums[((size_t)5 * N_PAD + n) * FDIM + lane] = v5;
  if (lane == 0) {
    cnt[(size_t)0 * N_NODES + n] = (float)c0;
    cnt[(size_t)1 * N_NODES + n] = (float)c1;
    cnt[(size_t)2 * N_NODES + n] = (float)c2;
    cnt[(size_t)3 * N_NODES + n] = (float)c3;
    cnt[(size_t)4 * N_NODES + n] = (float)c4;
    cnt[(size_t)5 * N_NODES + n] = (float)c5;
  }
}

// ===== r16 gemm (rolled two-plane staging, measured ~90-97us; r14/r19
// proved explicit pipelining explodes VGPR: 76/405us, 216/1143us).
// Only change vs r16: sums rows at stride N_PAD -> staging guard dropped
// (garbage rows feed only invalid lanes, never stored). =====
template <int OUTF, int JBLK>
__global__ __launch_bounds__(256) void k_gemm_tile2(
    const float* __restrict__ sums, const float* __restrict__ cnt,
    const float* __restrict__ W, const float* __restrict__ bias,
    float* __restrict__ out)
{
  __shared__ float lds[2][64 * PADF];   // 2 planes x 17408 B
  const int tid = threadIdx.x;
  const int lane = tid & 63;
  const int n0 = blockIdx.x * 64;
  const int jb = RFL(tid >> 6) * JBLK;

  int n = n0 + lane;
  const bool valid = (n < N_NODES);
  if (!valid) n = N_NODES - 1;

  float acc[JBLK];
  #pragma unroll
  for (int j = 0; j < JBLK; ++j) acc[j] = bias[jb + j];

  #pragma unroll 1
  for (int tp = 0; tp < T_STEPS / 2; ++tp) {
    __syncthreads();   // previous pair fully consumed before overwrite
    // stage planes t=2tp, 2tp+1: 2048 items, 8 per thread, all loads first
    float4 reg[8];
    #pragma unroll
    for (int it = 0; it < 8; ++it) {
      const int item = tid + it * 256;
      const int q = item & 15;
      const int u = (item >> 4) & 63;
      const int pl = item >> 10;
      reg[it] = *(const float4*)(sums + ((size_t)(2 * tp + pl) * N_PAD + n0 + u) * FDIM + q * 4);
    }
    #pragma unroll
    for (int it = 0; it < 8; ++it) {
      const int item = tid + it * 256;
      const int q = item & 15;
      const int u = (item >> 4) & 63;
      const int pl = item >> 10;
      *(float4*)(&lds[pl][u * PADF + q * 4]) = reg[it];
    }
    __syncthreads();

    #pragma unroll
    for (int pl = 0; pl < 2; ++pl) {
      const int t = 2 * tp + pl;

      // ---- pass A for this t (verbatim r1 rounding) ----
      const float c  = cnt[(size_t)t * N_NODES + n];
      const float rc = 1.0f / fmaxf(c, 1.0f);
      const float4* row = (const float4*)(&lds[pl][lane * PADF]);
      float ss = 0.0f;
      #pragma unroll
      for (int q = 0; q < FDIM / 4; ++q) {
        float4 v = row[q];
        float m0 = v.x * rc, m1 = v.y * rc, m2 = v.z * rc, m3 = v.w * rc;
        ss += m0 * m0 + m1 * m1 + m2 * m2 + m3 * m3;
      }
      const float norm = 1.0f - C2 * ss;
      const float s = rc / norm;

      // ---- pass B partial for this t, j-slice [jb, jb+JBLK) ----
      #pragma unroll
      for (int q8 = 0; q8 < FDIM / 8; ++q8) {
        const float4 a = row[q8 * 2 + 0];
        const float4 b4 = row[q8 * 2 + 1];
        const float hv[8] = {a.x, a.y, a.z, a.w, b4.x, b4.y, b4.z, b4.w};
        const float* wr = W + ((size_t)t * FDIM + q8 * 8) * OUTF + jb;
        #pragma unroll
        for (int i = 0; i < 8; ++i) {
          const float hs = hv[i] * s;
          #pragma unroll
          for (int j = 0; j < JBLK; ++j)
            acc[j] = fmaf(hs, wr[i * OUTF + j], acc[j]);
        }
      }
    }
  }

  if (valid) {
    float* o = out + (size_t)n * OUTF + jb;
    #pragma unroll
    for (int j = 0; j < JBLK; ++j) o[j] = fmaxf(acc[j], 0.0f);
  }
}

extern "C" void kernel_launch(void* const* d_in, const int* in_sizes, int n_in,
                              void* d_out, int out_size, void* d_ws, size_t ws_size,
                              hipStream_t stream) {
  const float* x  = (const float*)d_in[0];
  const int*  ei  = (const int*)d_in[1];
  const int*  tix = (const int*)d_in[2];
  const float* W1 = (const float*)d_in[3];
  const float* b1 = (const float*)d_in[4];
  const float* W2 = (const float*)d_in[5];
  const float* b2 = (const float*)d_in[6];

  const int* src = ei;
  const int* dst = ei + N_EDGES;

  // Workspace: head[SEG] | nxt[NE] | sums[6*N_PAD*64] | cnt[SEG] | h1[N_PAD*64]
  int*   head = (int*)d_ws;
  int*   nxt  = head + SEG;
  float* sums = (float*)(nxt + N_EDGES);
  float* cnt  = sums + (size_t)T_STEPS * N_PAD * FDIM;
  float* h1   = cnt + SEG;

  const int sum_grid = (N_NODES + 3) / 4;        // k_sum6: 4 waves/block
  const int ngrp     = (N_NODES + 63) / 64;      // 1563 64-node groups

  hipMemsetAsync(head, 0xFF, (size_t)SEG * sizeof(int), stream);
  k_build<<<(N_EDGES + 255) / 256, 256, 0, stream>>>(dst, tix, head, nxt);

  // Layer 1
  k_sum6<<<sum_grid, 256, 0, stream>>>(x, src, head, nxt, sums, cnt);
  k_gemm_tile2<64, 16><<<ngrp, 256, 0, stream>>>(sums, cnt, W1, b1, h1);

  // Layer 2 (same edge lists; cnt identical but rewritten -- harmless)
  k_sum6<<<sum_grid, 256, 0, stream>>>(h1, src, head, nxt, sums, cnt);
  k_gemm_tile2<16, 4><<<ngrp, 256, 0, stream>>>(sums, cnt, W2, b2, (float*)d_out);
}